// Round 18
// baseline (2490.193 us; speedup 1.0000x reference)
//
#include <hip/hip_runtime.h>
#include <hip/hip_bf16.h>
#include <stdint.h>

// ---- problem constants ----
#define BB   8
#define SS   512
#define HH   768
#define LL   12
#define NHH  12
#define DHH  64
#define FFF  3072
#define VV   21128
#define PAD_ID 0
#define SEP_ID 102
#define BS   (BB*SS)              // 4096
#define BSH  ((size_t)BS*HH)      // 3,145,728
#define BSFF ((size_t)BS*FFF)     // 12,582,912
#define QKVN (3*HH)               // 2304

using bf16 = __hip_bfloat16;
typedef __attribute__((ext_vector_type(8))) short short8;
typedef __attribute__((ext_vector_type(4))) short short4v;
typedef __attribute__((ext_vector_type(4))) float f32x4;

__device__ __forceinline__ f32x4 Z4() { f32x4 z = {0.f, 0.f, 0.f, 0.f}; return z; }

// async global->LDS, 16B per lane. LDS dest must be wave-uniform base + lane*16.
__device__ __forceinline__ void gload16(void* lds, const void* g) {
    __builtin_amdgcn_global_load_lds(
        (const __attribute__((address_space(1))) uint32_t*)g,
        (__attribute__((address_space(3))) uint32_t*)(uint32_t)(uintptr_t)lds,
        16, 0, 0);
}

template <int N>
__device__ __forceinline__ void waitvm() {
    if constexpr (N == 0) asm volatile("s_waitcnt vmcnt(0)" ::: "memory");
    else if constexpr (N == 2) asm volatile("s_waitcnt vmcnt(2)" ::: "memory");
    else if constexpr (N == 3) asm volatile("s_waitcnt vmcnt(3)" ::: "memory");
    else if constexpr (N == 4) asm volatile("s_waitcnt vmcnt(4)" ::: "memory");
    else if constexpr (N == 6) asm volatile("s_waitcnt vmcnt(6)" ::: "memory");
    else asm volatile("s_waitcnt vmcnt(8)" ::: "memory");
    __builtin_amdgcn_sched_barrier(0);
}

__device__ __forceinline__ void barrier_raw() {
    __builtin_amdgcn_s_barrier();
    __builtin_amdgcn_sched_barrier(0);
}

__device__ __forceinline__ void wait_vm0_lgkm0_barrier() {
    asm volatile("s_waitcnt vmcnt(0) lgkmcnt(0)" ::: "memory");
    __builtin_amdgcn_sched_barrier(0);
    __builtin_amdgcn_s_barrier();
    __builtin_amdgcn_sched_barrier(0);
}

// ---------------------------------------------------------------------------
// qlen[b] = (first j with ids[b,j]==SEP else 0) + 1
// ---------------------------------------------------------------------------
__global__ void __launch_bounds__(256) qlen_kernel(const int* __restrict__ ids,
                                                   int* __restrict__ qlen) {
    int b = blockIdx.x, tid = threadIdx.x;
    __shared__ int red[256];
    int best = 1 << 30;
    for (int j = tid; j < SS; j += 256)
        if (ids[b * SS + j] == SEP_ID) best = min(best, j);
    red[tid] = best; __syncthreads();
    for (int off = 128; off > 0; off >>= 1) {
        if (tid < off) red[tid] = min(red[tid], red[tid + off]);
        __syncthreads();
    }
    if (tid == 0) qlen[b] = (red[0] == (1 << 30) ? 0 : red[0]) + 1;
}

// ---------------------------------------------------------------------------
// embedding gather + LN -> hb (bf16). Wave-per-token, f32x4 loads (R17).
// ---------------------------------------------------------------------------
__global__ void __launch_bounds__(256) embed_ln_kernel(
    const int* __restrict__ ids, const float* __restrict__ we,
    const float* __restrict__ pe, const float* __restrict__ te,
    const float* __restrict__ g, const float* __restrict__ bt,
    bf16* __restrict__ hb) {
    int tid = threadIdx.x, lane = tid & 63, w = tid >> 6;
    int token = blockIdx.x * 4 + w;
    int s = token & (SS - 1);
    int id = ids[token];
    const float* wrow = we + (size_t)id * HH;
    const float* prow = pe + (size_t)s * HH;
    f32x4 x[3];
    float sum = 0.f;
#pragma unroll
    for (int i = 0; i < 3; ++i) {
        int j = (lane + i * 64) * 4;
        f32x4 a = *(const f32x4*)(wrow + j);
        f32x4 b = *(const f32x4*)(prow + j);
        f32x4 c = *(const f32x4*)(te + j);
        f32x4 v = a + b + c;
        x[i] = v;
        sum += v[0] + v[1] + v[2] + v[3];
    }
#pragma unroll
    for (int off = 1; off < 64; off <<= 1) sum += __shfl_xor(sum, off);
    float mu = sum * (1.0f / HH);
    float vs = 0.f;
#pragma unroll
    for (int i = 0; i < 3; ++i)
#pragma unroll
        for (int e = 0; e < 4; ++e) { float d = x[i][e] - mu; vs += d * d; }
#pragma unroll
    for (int off = 1; off < 64; off <<= 1) vs += __shfl_xor(vs, off);
    float rstd = rsqrtf(vs * (1.0f / HH) + 1e-12f);
    size_t base = (size_t)token * HH;
#pragma unroll
    for (int i = 0; i < 3; ++i) {
        int j = (lane + i * 64) * 4;
        f32x4 gg = *(const f32x4*)(g + j);
        f32x4 bb = *(const f32x4*)(bt + j);
        short4v yb;
#pragma unroll
        for (int e = 0; e < 4; ++e) {
            float y = (x[i][e] - mu) * rstd * gg[e] + bb[e];
            yb[e] = (short)__bfloat16_as_ushort(__float2bfloat16(y));
        }
        *(short4v*)(hb + base + j) = yb;
    }
}

// ---------------------------------------------------------------------------
// hb = LN(hb + proj + proj2)  (all bf16 in HBM; math in f32)
// wave-per-token (4 tokens/block), 64-lane shfl reduce (R12/R16).
// ---------------------------------------------------------------------------
__global__ void __launch_bounds__(256) add_ln_kernel(
    bf16* __restrict__ hb, const bf16* __restrict__ proj,
    const bf16* __restrict__ proj2,
    const float* __restrict__ g, const float* __restrict__ bt) {
    int tid = threadIdx.x, lane = tid & 63, w = tid >> 6;
    size_t token = (size_t)blockIdx.x * 4 + w;
    size_t base = token * HH;
    f32x4 x[3];
    float s = 0.f;
#pragma unroll
    for (int i = 0; i < 3; ++i) {
        int j = (lane + i * 64) * 4;
        short4v pa = *(const short4v*)(hb + base + j);
        short4v pb = *(const short4v*)(proj + base + j);
        short4v pc = *(const short4v*)(proj2 + base + j);
        f32x4 v;
#pragma unroll
        for (int e = 0; e < 4; ++e) {
            v[e] = __bfloat162float(__ushort_as_bfloat16((unsigned short)pa[e])) +
                   __bfloat162float(__ushort_as_bfloat16((unsigned short)pb[e])) +
                   __bfloat162float(__ushort_as_bfloat16((unsigned short)pc[e]));
        }
        x[i] = v;
        s += v[0] + v[1] + v[2] + v[3];
    }
#pragma unroll
    for (int off = 1; off < 64; off <<= 1) s += __shfl_xor(s, off);
    float mu = s * (1.0f / HH);
    float vs = 0.f;
#pragma unroll
    for (int i = 0; i < 3; ++i)
#pragma unroll
        for (int e = 0; e < 4; ++e) { float d = x[i][e] - mu; vs += d * d; }
#pragma unroll
    for (int off = 1; off < 64; off <<= 1) vs += __shfl_xor(vs, off);
    float rstd = rsqrtf(vs * (1.0f / HH) + 1e-12f);
#pragma unroll
    for (int i = 0; i < 3; ++i) {
        int j = (lane + i * 64) * 4;
        f32x4 gg = *(const f32x4*)(g + j);
        f32x4 bb = *(const f32x4*)(bt + j);
        short4v yb;
#pragma unroll
        for (int e = 0; e < 4; ++e) {
            float y = (x[i][e] - mu) * rstd * gg[e] + bb[e];
            yb[e] = (short)__bfloat16_as_ushort(__float2bfloat16(y));
        }
        *(short4v*)(hb + base + j) = yb;
    }
}

// ---------------------------------------------------------------------------
// transpose-convert: in f32 [K][N] (row-major) -> out bf16 [N][K]
// 16B short8 stores (R17).
// ---------------------------------------------------------------------------
__global__ void __launch_bounds__(256) transp_conv(
    const float* __restrict__ in, bf16* __restrict__ out,
    int K, int N, size_t inStride, size_t outStride) {
    const float* src = in + (size_t)blockIdx.z * inStride;
    bf16* dst = out + (size_t)blockIdx.z * outStride;
    __shared__ float t[64][65];          // [n_local][k_local]
    int n0 = blockIdx.x * 64, k0 = blockIdx.y * 64;
    int tid = threadIdx.x;
    {
        int r = tid >> 4, c4 = (tid & 15) * 4;
#pragma unroll
        for (int i = 0; i < 4; ++i) {
            int kk = k0 + r + i * 16;    // always < K
            int n = n0 + c4;
            float4 v;
            if (n + 3 < N) {
                v = *(const float4*)(src + (size_t)kk * N + n);
            } else {
                v.x = (n + 0 < N) ? src[(size_t)kk * N + n + 0] : 0.f;
                v.y = (n + 1 < N) ? src[(size_t)kk * N + n + 1] : 0.f;
                v.z = (n + 2 < N) ? src[(size_t)kk * N + n + 2] : 0.f;
                v.w = (n + 3 < N) ? src[(size_t)kk * N + n + 3] : 0.f;
            }
            t[c4 + 0][r + i * 16] = v.x;
            t[c4 + 1][r + i * 16] = v.y;
            t[c4 + 2][r + i * 16] = v.z;
            t[c4 + 3][r + i * 16] = v.w;
        }
    }
    __syncthreads();
    {
        int r = tid >> 3, c8 = (tid & 7) * 8;    // 32 n-rows per pass, 16B/lane
#pragma unroll
        for (int i = 0; i < 2; ++i) {
            int nn = n0 + r + i * 32;
            if (nn < N) {
                short8 o;
#pragma unroll
                for (int e = 0; e < 8; ++e)
                    o[e] = (short)__bfloat16_as_ushort(
                        __float2bfloat16(t[r + i * 32][c8 + e]));
                *(short8*)(dst + (size_t)nn * K + k0 + c8) = o;
            }
        }
    }
}

// ---------------------------------------------------------------------------
// v slice of qkv [BS][ldv] bf16 -> vT [B][NH][DH][S] bf16 (short4 both ways)
// ---------------------------------------------------------------------------
__global__ void __launch_bounds__(256) vtrans_kernel(const bf16* __restrict__ v,
                                                     bf16* __restrict__ vT,
                                                     int ldv) {
    __shared__ bf16 t[64][68];           // [d_local][s_local]
    int s0 = blockIdx.x * 64, h = blockIdx.y, b = blockIdx.z;
    int tid = threadIdx.x;
    int r = tid >> 4, c4 = (tid & 15) * 4;
#pragma unroll
    for (int i = 0; i < 4; ++i) {
        int sr = r + i * 16;             // s_local
        short4v x = *(const short4v*)(v + ((size_t)(b * SS + s0 + sr)) * ldv +
                                      h * 64 + c4);
        t[c4 + 0][sr] = __ushort_as_bfloat16((unsigned short)x[0]);
        t[c4 + 1][sr] = __ushort_as_bfloat16((unsigned short)x[1]);
        t[c4 + 2][sr] = __ushort_as_bfloat16((unsigned short)x[2]);
        t[c4 + 3][sr] = __ushort_as_bfloat16((unsigned short)x[3]);
    }
    __syncthreads();
#pragma unroll
    for (int i = 0; i < 4; ++i) {
        int dr = r + i * 16;             // d_local
        short4v o;
        o[0] = (short)__bfloat16_as_ushort(t[dr][c4 + 0]);
        o[1] = (short)__bfloat16_as_ushort(t[dr][c4 + 1]);
        o[2] = (short)__bfloat16_as_ushort(t[dr][c4 + 2]);
        o[3] = (short)__bfloat16_as_ushort(t[dr][c4 + 3]);
        *(short4v*)(vT + (((size_t)(b * NHH + h)) * 64 + dr) * SS + s0 + c4) = o;
    }
}

// ---------------------------------------------------------------------------
// cls 256x256 GEMM, BK=32, 4-buffer depth-3 counted-vmcnt pipeline (R12).
// R18: GRPM=16 (full-M column-major raster within XCD chunk) — A (6.3MB bf16)
// is L2/L3-resident, so walking all 16 m-blocks per n-column streams B exactly
// once (FETCH 109MB -> ~45MB predicted).
// ---------------------------------------------------------------------------
template <int KK, int LDA, int LDB, int LDC, int NN, int GRPM>
__global__ void __launch_bounds__(512, 1) gemm256k_kernel(
    const bf16* __restrict__ A, const bf16* __restrict__ BT,
    const float* __restrict__ bias, float* __restrict__ Cout) {
    constexpr int ABYTES = 256 * 64;     // 256 rows x 32 bf16
    constexpr int BUF = 2 * ABYTES;      // A + B per buffer = 32KB
    constexpr int LPS = 4;               // 2 A + 2 B issues per thread
    __shared__ __align__(16) char smem[4 * BUF];
    int tid = threadIdx.x, lane = tid & 63, wid = tid >> 6;
    int mg = wid >> 2, ng = wid & 3;

    // T1: XCD chunk, then GRPM-tall column-major raster
    int gN = gridDim.x, gM = gridDim.y;
    int nwg = gN * gM;
    int bid = blockIdx.y * gN + blockIdx.x;
    int swz = ((nwg & 7) == 0) ? ((bid & 7) * (nwg >> 3) + (bid >> 3)) : bid;
    int width = GRPM * gN;
    int grp = swz / width, rem = swz % width;
    int gh = min(GRPM, gM - grp * GRPM);
    int by = grp * GRPM + rem % gh;
    int bx = rem / gh;
    int m0 = by * 256, n0 = bx * 256;

    const char* Ab = (const char*)A;
    const char* Bb = (const char*)BT;

    f32x4 acc[8][4];
#pragma unroll
    for (int i = 0; i < 8; ++i)
#pragma unroll
        for (int j = 0; j < 4; ++j) acc[i][j] = Z4();

    auto stage = [&](int k0, int sel) {
#pragma unroll
        for (int i = 0; i < 2; ++i) {
            int lin = tid * 16 + i * 8192;
            int row = lin >> 6, slot = (lin >> 4) & 3;
            gload16(smem + sel * BUF + lin,
                    Ab + ((size_t)(m0 + row) * LDA + k0) * 2 +
                        ((slot ^ ((row >> 1) & 3)) << 4));
        }
#pragma unroll
        for (int i = 0; i < 2; ++i) {
            int lin = tid * 16 + i * 8192;
            int row = lin >> 6, slot = (lin >> 4) & 3;
            int nr = n0 + row;
            if constexpr (NN % 256 != 0) { if (nr >= NN) nr = NN - 1; }
            gload16(smem + sel * BUF + ABYTES + lin,
                    Bb + ((size_t)nr * LDB + k0) * 2 +
                        ((slot ^ ((row >> 1) & 3)) << 4));
        }
    };

    constexpr int T = KK / 32;
    stage(0, 0);
    stage(32, 1);
    stage(64, 2);
    waitvm<2 * LPS>();          // oldest (buf0) landed; buf1,2 in flight
    barrier_raw();

    for (int t = 0; t < T; ++t) {
        if (t + 3 < T) stage((t + 3) * 32, (t + 3) & 3);

        const char* Ar = smem + (t & 3) * BUF;
        const char* Br = Ar + ABYTES;
        short8 af[8], bfr[4];
#pragma unroll
        for (int i = 0; i < 8; ++i) {
            int ar = mg * 128 + i * 16 + (lane & 15);
            int slot = (lane >> 4) ^ ((ar >> 1) & 3);
            af[i] = *(const short8*)(Ar + ar * 64 + slot * 16);
        }
#pragma unroll
        for (int j = 0; j < 4; ++j) {
            int br = ng * 64 + j * 16 + (lane & 15);
            int slot = (lane >> 4) ^ ((br >> 1) & 3);
            bfr[j] = *(const short8*)(Br + br * 64 + slot * 16);
        }
        __builtin_amdgcn_s_setprio(1);
#pragma unroll
        for (int i = 0; i < 8; ++i)
#pragma unroll
            for (int j = 0; j < 4; ++j)
                acc[i][j] = __builtin_amdgcn_mfma_f32_16x16x32_bf16(
                    af[i], bfr[j], acc[i][j], 0, 0, 0);
        __builtin_amdgcn_s_setprio(0);

        if (t + 1 < T) {
            if (t + 4 < T)      waitvm<2 * LPS>();   // {t+2,t+3} stay in flight
            else if (t + 3 < T) waitvm<LPS>();
            else                waitvm<0>();
            barrier_raw();
        }
    }

    // direct-store epilogue (f32 out, N-tail guarded)
#pragma unroll
    for (int i = 0; i < 8; ++i)
#pragma unroll
        for (int r = 0; r < 4; ++r) {
            int m = m0 + mg * 128 + i * 16 + (lane >> 4) * 4 + r;
#pragma unroll
            for (int j = 0; j < 4; ++j) {
                int n = n0 + ng * 64 + j * 16 + (lane & 15);
                if ((NN % 256 == 0) || n < NN) {
                    float v = acc[i][j][r] + bias[n];
                    Cout[(size_t)m * LDC + n] = v;
                }
            }
        }
}

// ---------------------------------------------------------------------------
// bf16 MFMA GEMM (R10-proven): THREADS-parameterized 128-tile, 3-stage counted
// vmcnt pipeline, slot swizzle (row>>1)&3, XCD+GROUP_M=8 raster, direct stores.
// split-K over blockIdx.z; bf16 output honors zStride (R15).
// ---------------------------------------------------------------------------
#define GBK 32

template <int THREADS, int TBM, int TBN, int OUT_BF16, int ACT, int KK,
          int LDA, int LDB, int LDC, int NN, int NSTAGES>
__global__ void __launch_bounds__(THREADS) gemm_bf16_kernel(
    const bf16* __restrict__ A, const bf16* __restrict__ BT,
    const float* __restrict__ bias, void* __restrict__ Cout, size_t zStride) {
    constexpr int WN = (THREADS == 512) ? 4 : 2;
    constexpr int WM = 2;
    constexpr int MFRAG = TBM / WM / 16;
    constexpr int NFRAG = TBN / WN / 16;
    constexpr int ABYTES = TBM * GBK * 2;
    constexpr int BBYTES = TBN * GBK * 2;
    constexpr int A_ISS = ABYTES / (THREADS * 16);
    constexpr int B_ISS = BBYTES / (THREADS * 16);
    constexpr int LPS = A_ISS + B_ISS;
    __shared__ __align__(16) char smem[NSTAGES * (ABYTES + BBYTES)];
    char* Asm = smem;
    char* Bsm = smem + NSTAGES * ABYTES;
    int tid = threadIdx.x;
    int lane = tid & 63, wid = tid >> 6;

    int zz = blockIdx.z;
    const char* Ab = (const char*)(A + (size_t)zz * KK);
    const char* Bb = (const char*)(BT + (size_t)zz * KK);

    int gN = gridDim.x, gM = gridDim.y;
    int nwg = gN * gM;
    int bid = blockIdx.y * gN + blockIdx.x;
    int swz = ((nwg & 7) == 0) ? ((bid & 7) * (nwg >> 3) + (bid >> 3)) : bid;
    int width = 8 * gN;
    int grp = swz / width, rem = swz % width;
    int gh = min(8, gM - grp * 8);
    int by = grp * 8 + rem % gh;
    int bx = rem / gh;

    int m0 = by * TBM, n0 = bx * TBN;
    int wr = (wid / WN) * (TBM / WM);
    int wc = (wid % WN) * (TBN / WN);

    f32x4 acc[MFRAG][NFRAG];
#pragma unroll
    for (int i = 0; i < MFRAG; ++i)
#pragma unroll
        for (int j = 0; j < NFRAG; ++j) acc[i][j] = Z4();

    auto stage = [&](int k0, int sel) {
#pragma unroll
        for (int i = 0; i < A_ISS; ++i) {
            int lin = tid * 16 + i * (THREADS * 16);
            int row = lin >> 6, slot = (lin >> 4) & 3;
            gload16(Asm + sel * ABYTES + lin,
                    Ab + ((size_t)(m0 + row) * LDA + k0) * 2 +
                        ((slot ^ ((row >> 1) & 3)) << 4));
        }
#pragma unroll
        for (int i = 0; i < B_ISS; ++i) {
            int lin = tid * 16 + i * (THREADS * 16);
            int row = lin >> 6, slot = (lin >> 4) & 3;
            int nr = n0 + row;
            if constexpr (NN % TBN != 0) { if (nr >= NN) nr = NN - 1; }
            gload16(Bsm + sel * BBYTES + lin,
                    Bb + ((size_t)nr * LDB + k0) * 2 +
                        ((slot ^ ((row >> 1) & 3)) << 4));
        }
    };

    constexpr int T = KK / GBK;
#pragma unroll
    for (int s = 0; s < NSTAGES - 1; ++s) stage(s * GBK, s);
    waitvm<(NSTAGES - 2) * LPS>();
    barrier_raw();

    for (int t = 0; t < T; ++t) {
        if (t + NSTAGES - 1 < T)
            stage((t + NSTAGES - 1) * GBK, (t + NSTAGES - 1) % NSTAGES);

        const char* Ar = Asm + (t % NSTAGES) * ABYTES;
        const char* Br = Bsm + (t % NSTAGES) * BBYTES;
        short8 af[MFRAG], bfr[NFRAG];
#pragma unroll
        for (int i = 0; i < MFRAG; ++i) {
            int ar = wr + i * 16 + (lane & 15);
            int slot = (lane >> 4) ^ ((ar >> 1) & 3);
            af[i] = *(const short8*)(Ar + ar * 64 + slot * 16);
        }
#pragma unroll
        for (int j = 0; j < NFRAG; ++j) {
            int br = wc + j * 16 + (lane & 15);
            int slot = (lane >> 4) ^ ((br >> 1) & 3);
            bfr[j] = *(const short8*)(Br + br * 64 + slot * 16);
        }
#pragma unroll
        for (int i = 0; i < MFRAG; ++i)
#pragma unroll
            for (int j = 0; j < NFRAG; ++j)
                acc[i][j] = __builtin_amdgcn_mfma_f32_16x16x32_bf16(
                    af[i], bfr[j], acc[i][j], 0, 0, 0);

        if (t + 1 < T) {
            if (t + 2 < T) waitvm<LPS>();
            else           waitvm<0>();
            barrier_raw();
        }
    }

    bool nfull = (NN % TBN == 0) || (n0 + TBN <= NN);
#pragma unroll
    for (int i = 0; i < MFRAG; ++i) {
#pragma unroll
        for (int r = 0; r < 4; ++r) {
            int m = m0 + wr + i * 16 + (lane >> 4) * 4 + r;
#pragma unroll
            for (int j = 0; j < NFRAG; ++j) {
                int n = n0 + wc + j * 16 + (lane & 15);
                if (nfull || n < NN) {
                    float v = acc[i][j][r] + ((zz == 0) ? bias[n] : 0.f);
                    if (ACT) v = 0.5f * v * (1.0f + erff(v * 0.70710678118654752f));
                    if (OUT_BF16)
                        ((bf16*)Cout)[zz * zStride + (size_t)m * LDC + n] =
                            __float2bfloat16(v);
                    else
                        ((float*)Cout)[zz * zStride + (size_t)m * LDC + n] = v;
                }
            }
        }
    }
}

// ---------------------------------------------------------------------------
// flash attention, bf16 MFMA. Block = 64 q-rows (4 waves x 16), KV tiles of 64,
// double-buffered. Causal tile skip for q-blocks 1..5 (R13, bit-exact).
// ---------------------------------------------------------------------------
__global__ void __launch_bounds__(256) attn_mfma_kernel(
    const bf16* __restrict__ Q, const bf16* __restrict__ K,
    const bf16* __restrict__ VT, const int* __restrict__ ids,
    const int* __restrict__ qlen, bf16* __restrict__ att, int ld) {
    __shared__ __align__(16) bf16 Qs[64 * 64];
    __shared__ __align__(16) bf16 Ks[2][64 * 64];
    __shared__ __align__(16) bf16 Vs[2][64 * 64];
    __shared__ __align__(16) bf16 Ps[4 * 16 * 64];
    __shared__ float padj[2][64];

    int tid = threadIdx.x, lane = tid & 63, w = tid >> 6;
    int q0 = blockIdx.x * 64, h = blockIdx.y, b = blockIdx.z;
    int ql = qlen[b];

    int qb = q0 >> 6;
    int kvEnd = (qb >= 1 && qb <= 5) ? (qb + 1) * 64 : SS;

    const char* kbase0 = (const char*)K + ((size_t)(b * SS) * ld) * 2;
    const char* vbase0 = (const char*)VT + (((size_t)(b * NHH + h)) * 64) * SS * 2;

    auto stageKV = [&](int kv0, int sel) {
        int lin = tid * 16;
#pragma unroll
        for (int i = 0; i < 2; ++i, lin += 4096) {
            int row = lin >> 7, bir = lin & 127;
            int sbir = bir ^ ((row & 7) << 4);
            gload16((char*)Ks[sel] + lin,
                    kbase0 + (size_t)(kv0 + row) * (ld * 2) + h * 128 + sbir);
            gload16((char*)Vs[sel] + lin,
                    vbase0 + (size_t)row * (SS * 2) + (size_t)kv0 * 2 + sbir);
        }
        if (tid < 64)
            padj[sel][tid] = (ids[b * SS + kv0 + tid] != PAD_ID) ? 1.f : 0.f;
    };

    {
        const char* qbase =
            (const char*)Q + ((size_t)(b * SS + q0) * ld) * 2 + h * 128;
        int lin = tid * 16;
#pragma unroll
        for (int i = 0; i < 2; ++i, lin += 4096) {
            int row = lin >> 7, bir = lin & 127;
            int sbir = bir ^ ((row & 7) << 4);
            gload16((char*)Qs + lin, qbase + (size_t)row * (ld * 2) + sbir);
        }
    }
    stageKV(0, 0);
    int qrow_base = q0 + w * 16 + (lane >> 4) * 4;   // + r
    bool padq[4];
#pragma unroll
    for (int r = 0; r < 4; ++r)
        padq[r] = (ids[b * SS + qrow_base + r] != PAD_ID);

    wait_vm0_lgkm0_barrier();

    short8 aq[2];
#pragma unroll
    for (int ks = 0; ks < 2; ++ks) {
        int row = w * 16 + (lane & 15);
        int bir = ks * 64 + (lane >> 4) * 16;
        aq[ks] = *(const short8*)((const char*)Qs + row * 128 +
                                  (bir ^ ((row & 7) << 4)));
    }

    float m_run[4], l_run[4];
    f32x4 accO[4];
#pragma unroll
    for (int r = 0; r < 4; ++r) { m_run[r] = -1e30f; l_run[r] = 0.f; }
#pragma unroll
    for (int d = 0; d < 4; ++d) accO[d] = Z4();

    int cur = 0;
    for (int kv0 = 0; kv0 < kvEnd; kv0 += 64) {
        if (kv0 + 64 < kvEnd) stageKV(kv0 + 64, cur ^ 1);
        const char* kb = (const char*)Ks[cur];
        const char* vb = (const char*)Vs[cur];

        f32x4 accS[4];
        __builtin_amdgcn_s_setprio(1);
#pragma unroll
        for (int nf = 0; nf < 4; ++nf) {
            f32x4 z = Z4();
#pragma unroll
            for (int ks = 0; ks < 2; ++ks) {
                int row = nf * 16 + (lane & 15);
                int bir = ks * 64 + (lane >> 4) * 16;
                short8 bk = *(const short8*)(kb + row * 128 +
                                             (bir ^ ((row & 7) << 4)));
                z = __builtin_amdgcn_mfma_f32_16x16x32_bf16(aq[ks], bk, z, 0, 0, 0);
            }
            accS[nf] = z;
        }
        __builtin_amdgcn_s_setprio(0);

        float p[4][4];        // [r][nf]
#pragma unroll
        for (int r = 0; r < 4; ++r) {
            int qg = qrow_base + r;
            float mx = -1e30f;
#pragma unroll
            for (int nf = 0; nf < 4; ++nf) {
                int j = kv0 + nf * 16 + (lane & 15);
                bool ok = padq[r] && (padj[cur][nf * 16 + (lane & 15)] != 0.f) &&
                          ((qg < ql) || (j < ql) || (j <= qg));
                float s = accS[nf][r] * 0.125f + (ok ? 0.f : -1e9f);
                p[r][nf] = s;
                mx = fmaxf(mx, s);
            }
#pragma unroll
            for (int off = 1; off < 16; off <<= 1)
                mx = fmaxf(mx, __shfl_xor(mx, off));
            float mnew = fmaxf(m_run[r], mx);
            float fac = __expf(m_run[r] - mnew);
            m_run[r] = mnew;
            float rs = 0.f;
#pragma unroll
            for (int nf = 0; nf < 4; ++nf) {
                float e = __expf(p[r][nf] - mnew);
                p[r][nf] = e;
                rs += e;
            }
#pragma unroll
            for (int off = 1; off < 16; off <<= 1)
                rs += __shfl_xor(rs, off);
            l_run[r] = l_run[r] * fac + rs;
#pragma unroll
            for (int df = 0; df < 4; ++df) accO[df][r] *= fac;
        }

#pragma unroll
        for (int r = 0; r < 4; ++r) {
            int prow = (lane >> 4) * 4 + r;
#pragma unroll
            for (int nf = 0; nf < 4; ++nf) {
                int c = nf * 16 + (lane & 15);
                int byte = (c * 2) ^ ((prow & 7) << 4);
                *(bf16*)((char*)Ps + w * 2048 + prow * 128 + byte) =
                    __float2bfloat16(p[r][nf]);
            }
        }
        asm volatile("s_waitcnt lgkmcnt(0)" ::: "memory");
        __builtin_amdgcn_sched_barrier(0);

        __builtin_amdgcn_s_setprio(1);
#pragma unroll
        for (int ks = 0; ks < 2; ++ks) {
            int prow = lane & 15;
            int bir = ks * 64 + (lane >> 4) * 16;
            short8 ap = *(const short8*)((const char*)Ps + w * 2048 + prow * 128 +
                                         (bir ^ ((prow & 7) << 4)));
#pragma unroll
            for (int df = 0; df < 4; ++df) {
                int vrow = df * 16 + (lane & 15);
                short8 bv = *(const short8*)(vb + vrow * 128 +
                                             (bir ^ ((vrow & 7) << 4)));
                accO[df] = __builtin_amdgcn_mfma_f32_16x16x32_bf16(
                    ap, bv, accO[df], 0, 0, 0);
            }
        }
        __builtin_amdgcn_s_setprio(0);

        if (kv0 + 64 < kvEnd) wait_vm0_lgkm0_barrier();
        cur ^= 1;
    }

#pragma unroll
    for (int r = 0; r < 4; ++r) {
        int qg = qrow_base + r;
        float inv = 1.0f / l_run[r];
#pragma unroll
        for (int df = 0; df < 4; ++df) {
            int d = df * 16 + (lane & 15);
            att[((size_t)(b * SS) + qg) * HH + h * 64 + d] =
                __float2bfloat16(accO[df][r] * inv);
        }
    }
}

// ---------------------------------------------------------------------------
// launch
// ---------------------------------------------------------------------------
extern "C" void kernel_launch(void* const* d_in, const int* in_sizes, int n_in,
                              void* d_out, int out_size, void* d_ws, size_t ws_size,
                              hipStream_t stream) {
    const int*   ids      = (const int*)d_in[0];
    const float* word_emb = (const float*)d_in[1];
    const float* pos_emb  = (const float*)d_in[2];
    const float* type_emb = (const float*)d_in[3];
    const float* emb_ln_g = (const float*)d_in[4];
    const float* emb_ln_b = (const float*)d_in[5];
    const float* attn_w   = (const float*)d_in[6];
    const float* attn_b   = (const float*)d_in[7];
    const float* ln1_g    = (const float*)d_in[8];
    const float* ln1_b    = (const float*)d_in[9];
    const float* ffn_w1   = (const float*)d_in[10];
    const float* ffn_b1   = (const float*)d_in[11];
    const float* ffn_w2   = (const float*)d_in[12];
    const float* ffn_b2   = (const float*)d_in[13];
    const float* ln2_g    = (const float*)d_in[14];
    const float* ln2_b    = (const float*)d_in[15];
    const float* cls_w    = (const float*)d_in[16];
    const float* cls_b    = (const float*)d_in[17];
    float* out = (float*)d_out;

    // ---- workspace layout ----
    char* base = (char*)d_ws;
    size_t off = 0;
    auto take = [&](size_t bytes) {
        char* r = base + off;
        off += (bytes + 255) & ~(size_t)255;
        return r;
    };
    bf16*  projb = (bf16*)take(2 * BSH * 2);      // bf16 split-K halves
    float* spare = (float*)take(BSH * 4);          // reusable span head (cls wrot)
    bf16*  qkv   = (bf16*)take((size_t)BS * QKVN * 2);  // [BS][2304]
    bf16*  vT    = (bf16*)take(BSH * 2);
    bf16*  attb  = (bf16*)take(BSH * 2);
    bf16*  ffb   = (bf16*)take(BSFF * 2);          // end of reusable span
    bf16*  hb    = (bf16*)take(BSH * 2);
    int*   qlen  = (int*)take(256);
    size_t commonEnd = off;

    const size_t szAttnW = (size_t)48 * HH * HH * 2;
    const size_t szW1    = (size_t)LL * HH * FFF * 2;
    const size_t szCls   = (size_t)VV * HH * 2;
    const size_t fullNeed = commonEnd + szAttnW + 2 * szW1 + szCls;
    bool fullMode = (ws_size >= fullNeed);

    bf16 *wAttnT = nullptr, *w1T = nullptr, *w2T = nullptr, *clsT = nullptr, *wrot = nullptr;
    if (fullMode) {
        wAttnT = (bf16*)take(szAttnW);
        w1T    = (bf16*)take(szW1);
        w2T    = (bf16*)take(szW1);
        clsT   = (bf16*)take(szCls);
    } else {
        wrot = (bf16*)take((size_t)HH * FFF * 2);   // rotating buffer
        clsT = (bf16*)spare;                         // cls weight -> dead span
    }

    auto convw = [&](const float* src, bf16* dst, int K, int N) {
        dim3 g((N + 63) / 64, K / 64, 1);
        transp_conv<<<g, 256, 0, stream>>>(src, dst, K, N, (size_t)0, (size_t)0);
    };

    qlen_kernel<<<BB, 256, 0, stream>>>(ids, qlen);

    if (fullMode) {
        transp_conv<<<dim3(12, 12, 48), 256, 0, stream>>>(
            attn_w, wAttnT, HH, HH, (size_t)HH * HH, (size_t)HH * HH);
        transp_conv<<<dim3(FFF / 64, HH / 64, LL), 256, 0, stream>>>(
            ffn_w1, w1T, HH, FFF, (size_t)HH * FFF, (size_t)HH * FFF);
        transp_conv<<<dim3(HH / 64, FFF / 64, LL), 256, 0, stream>>>(
            ffn_w2, w2T, FFF, HH, (size_t)HH * FFF, (size_t)HH * FFF);
        transp_conv<<<dim3((VV + 63) / 64, HH / 64, 1), 256, 0, stream>>>(
            cls_w, clsT, HH, VV, (size_t)0, (size_t)0);
    }

    embed_ln_kernel<<<BS / 4, 256, 0, stream>>>(ids, word_emb, pos_emb, type_emb,
                                                emb_ln_g, emb_ln_b, hb);

    dim3 gQKV(QKVN / 128, BS / 128, 1);          // 576, 512-thr
    dim3 gWo(HH / 64, BS / 128, 2);              // 768 (split-K x2), 256-thr
    dim3 gFF1(FFF / 128, BS / 128, 1);           // 768, 512-thr
    dim3 gFF2(HH / 64, BS / 128, 2);             // 768 (split-K x2), 256-thr
    dim3 gCls((VV + 255) / 256, BS / 256, 1);    // 83 x 16 = 1328, 512-thr
    dim3 gAttn(SS / 64, NHH, BB);                // 768
    dim3 gVT(SS / 64, NHH, BB);
    dim3 gLN(BS / 4, 1, 1);                      // 1024, wave-per-token

    for (int l = 0; l < LL; ++l) {
        const float* wq32 = attn_w + (size_t)l * 4 * HH * HH;
        const float* wo32 = wq32 + (size_t)3 * HH * HH;
        const float* bqkv = attn_b + (size_t)l * 4 * HH;   // q,k,v contiguous
        const float* bo   = bqkv + 3 * HH;

        bf16 *wqkvT, *woT, *w1Tl, *w2Tl;
        if (fullMode) {
            wqkvT = wAttnT + (size_t)(l * 4) * HH * HH;    // [2304][768]
            woT   = wAttnT + (size_t)(l * 4 + 3) * HH * HH;
            w1Tl  = w1T + (size_t)l * HH * FFF;
            w2Tl  = w2T + (size_t)l * HH * FFF;
        } else {
            wqkvT = woT = w1Tl = w2Tl = wrot;
        }

        if (!fullMode) {
            convw(wq32, wrot, HH, HH);
            convw(wq32 + (size_t)HH * HH, wrot + (size_t)HH * HH, HH, HH);
            convw(wq32 + (size_t)2 * HH * HH, wrot + (size_t)2 * HH * HH, HH, HH);
        }
        gemm_bf16_kernel<512, 128, 128, 1, 0, HH, HH, HH, QKVN, QKVN, 3>
            <<<gQKV, 512, 0, stream>>>(hb, wqkvT, bqkv, qkv, 0);

        vtrans_kernel<<<gVT, 256, 0, stream>>>(qkv + 2 * HH, vT, QKVN);
        attn_mfma_kernel<<<gAttn, 256, 0, stream>>>(
            qkv, qkv + HH, vT, ids, qlen, attb, QKVN);

        if (!fullMode) convw(wo32, wrot, HH, HH);
        gemm_bf16_kernel<256, 128, 64, 1, 0, HH / 2, HH, HH, HH, HH, 3>
            <<<gWo, 256, 0, stream>>>(attb, woT, bo, projb, BSH);
        add_ln_kernel<<<gLN, 256, 0, stream>>>(hb, projb, projb + BSH,
                                               ln1_g + (size_t)l * HH,
                                               ln1_b + (size_t)l * HH);

        if (!fullMode) convw(ffn_w1 + (size_t)l * HH * FFF, wrot, HH, FFF);
        gemm_bf16_kernel<512, 128, 128, 1, 1, HH, HH, HH, FFF, FFF, 3>
            <<<gFF1, 512, 0, stream>>>(hb, w1Tl, ffn_b1 + (size_t)l * FFF, ffb, 0);
        if (!fullMode) convw(ffn_w2 + (size_t)l * HH * FFF, wrot, FFF, HH);
        gemm_bf16_kernel<256, 128, 64, 1, 0, FFF / 2, FFF, FFF, HH, HH, 3>
            <<<gFF2, 256, 0, stream>>>(ffb, w2Tl, ffn_b2 + (size_t)l * HH, projb,
                                       BSH);
        add_ln_kernel<<<gLN, 256, 0, stream>>>(hb, projb, projb + BSH,
                                               ln2_g + (size_t)l * HH,
                                               ln2_b + (size_t)l * HH);
    }

    if (!fullMode) convw(cls_w, clsT, HH, VV);
    gemm256k_kernel<HH, HH, HH, VV, VV, 16>
        <<<gCls, 512, 0, stream>>>(hb, clsT, cls_b, out);
}

// Round 19
// 2482.369 us; speedup vs baseline: 1.0032x; 1.0032x over previous
//
#include <hip/hip_runtime.h>
#include <hip/hip_bf16.h>
#include <stdint.h>

// ---- problem constants ----
#define BB   8
#define SS   512
#define HH   768
#define LL   12
#define NHH  12
#define DHH  64
#define FFF  3072
#define VV   21128
#define PAD_ID 0
#define SEP_ID 102
#define BS   (BB*SS)              // 4096
#define BSH  ((size_t)BS*HH)      // 3,145,728
#define BSFF ((size_t)BS*FFF)     // 12,582,912
#define QKVN (3*HH)               // 2304

using bf16 = __hip_bfloat16;
typedef __attribute__((ext_vector_type(8))) short short8;
typedef __attribute__((ext_vector_type(4))) short short4v;
typedef __attribute__((ext_vector_type(4))) float f32x4;

__device__ __forceinline__ f32x4 Z4() { f32x4 z = {0.f, 0.f, 0.f, 0.f}; return z; }

// async global->LDS, 16B per lane. LDS dest must be wave-uniform base + lane*16.
__device__ __forceinline__ void gload16(void* lds, const void* g) {
    __builtin_amdgcn_global_load_lds(
        (const __attribute__((address_space(1))) uint32_t*)g,
        (__attribute__((address_space(3))) uint32_t*)(uint32_t)(uintptr_t)lds,
        16, 0, 0);
}

template <int N>
__device__ __forceinline__ void waitvm() {
    if constexpr (N == 0) asm volatile("s_waitcnt vmcnt(0)" ::: "memory");
    else if constexpr (N == 2) asm volatile("s_waitcnt vmcnt(2)" ::: "memory");
    else if constexpr (N == 3) asm volatile("s_waitcnt vmcnt(3)" ::: "memory");
    else if constexpr (N == 4) asm volatile("s_waitcnt vmcnt(4)" ::: "memory");
    else if constexpr (N == 6) asm volatile("s_waitcnt vmcnt(6)" ::: "memory");
    else asm volatile("s_waitcnt vmcnt(8)" ::: "memory");
    __builtin_amdgcn_sched_barrier(0);
}

__device__ __forceinline__ void barrier_raw() {
    __builtin_amdgcn_s_barrier();
    __builtin_amdgcn_sched_barrier(0);
}

__device__ __forceinline__ void wait_vm0_lgkm0_barrier() {
    asm volatile("s_waitcnt vmcnt(0) lgkmcnt(0)" ::: "memory");
    __builtin_amdgcn_sched_barrier(0);
    __builtin_amdgcn_s_barrier();
    __builtin_amdgcn_sched_barrier(0);
}

// ---------------------------------------------------------------------------
// qlen[b] = (first j with ids[b,j]==SEP else 0) + 1
// ---------------------------------------------------------------------------
__global__ void __launch_bounds__(256) qlen_kernel(const int* __restrict__ ids,
                                                   int* __restrict__ qlen) {
    int b = blockIdx.x, tid = threadIdx.x;
    __shared__ int red[256];
    int best = 1 << 30;
    for (int j = tid; j < SS; j += 256)
        if (ids[b * SS + j] == SEP_ID) best = min(best, j);
    red[tid] = best; __syncthreads();
    for (int off = 128; off > 0; off >>= 1) {
        if (tid < off) red[tid] = min(red[tid], red[tid + off]);
        __syncthreads();
    }
    if (tid == 0) qlen[b] = (red[0] == (1 << 30) ? 0 : red[0]) + 1;
}

// ---------------------------------------------------------------------------
// embedding gather + LN -> hb (bf16). Wave-per-token, f32x4 loads (R17).
// ---------------------------------------------------------------------------
__global__ void __launch_bounds__(256) embed_ln_kernel(
    const int* __restrict__ ids, const float* __restrict__ we,
    const float* __restrict__ pe, const float* __restrict__ te,
    const float* __restrict__ g, const float* __restrict__ bt,
    bf16* __restrict__ hb) {
    int tid = threadIdx.x, lane = tid & 63, w = tid >> 6;
    int token = blockIdx.x * 4 + w;
    int s = token & (SS - 1);
    int id = ids[token];
    const float* wrow = we + (size_t)id * HH;
    const float* prow = pe + (size_t)s * HH;
    f32x4 x[3];
    float sum = 0.f;
#pragma unroll
    for (int i = 0; i < 3; ++i) {
        int j = (lane + i * 64) * 4;
        f32x4 a = *(const f32x4*)(wrow + j);
        f32x4 b = *(const f32x4*)(prow + j);
        f32x4 c = *(const f32x4*)(te + j);
        f32x4 v = a + b + c;
        x[i] = v;
        sum += v[0] + v[1] + v[2] + v[3];
    }
#pragma unroll
    for (int off = 1; off < 64; off <<= 1) sum += __shfl_xor(sum, off);
    float mu = sum * (1.0f / HH);
    float vs = 0.f;
#pragma unroll
    for (int i = 0; i < 3; ++i)
#pragma unroll
        for (int e = 0; e < 4; ++e) { float d = x[i][e] - mu; vs += d * d; }
#pragma unroll
    for (int off = 1; off < 64; off <<= 1) vs += __shfl_xor(vs, off);
    float rstd = rsqrtf(vs * (1.0f / HH) + 1e-12f);
    size_t base = (size_t)token * HH;
#pragma unroll
    for (int i = 0; i < 3; ++i) {
        int j = (lane + i * 64) * 4;
        f32x4 gg = *(const f32x4*)(g + j);
        f32x4 bb = *(const f32x4*)(bt + j);
        short4v yb;
#pragma unroll
        for (int e = 0; e < 4; ++e) {
            float y = (x[i][e] - mu) * rstd * gg[e] + bb[e];
            yb[e] = (short)__bfloat16_as_ushort(__float2bfloat16(y));
        }
        *(short4v*)(hb + base + j) = yb;
    }
}

// ---------------------------------------------------------------------------
// hb = LN(hb + proj + proj2)  (all bf16 in HBM; math in f32)
// wave-per-token (4 tokens/block), 64-lane shfl reduce (R12/R16).
// ---------------------------------------------------------------------------
__global__ void __launch_bounds__(256) add_ln_kernel(
    bf16* __restrict__ hb, const bf16* __restrict__ proj,
    const bf16* __restrict__ proj2,
    const float* __restrict__ g, const float* __restrict__ bt) {
    int tid = threadIdx.x, lane = tid & 63, w = tid >> 6;
    size_t token = (size_t)blockIdx.x * 4 + w;
    size_t base = token * HH;
    f32x4 x[3];
    float s = 0.f;
#pragma unroll
    for (int i = 0; i < 3; ++i) {
        int j = (lane + i * 64) * 4;
        short4v pa = *(const short4v*)(hb + base + j);
        short4v pb = *(const short4v*)(proj + base + j);
        short4v pc = *(const short4v*)(proj2 + base + j);
        f32x4 v;
#pragma unroll
        for (int e = 0; e < 4; ++e) {
            v[e] = __bfloat162float(__ushort_as_bfloat16((unsigned short)pa[e])) +
                   __bfloat162float(__ushort_as_bfloat16((unsigned short)pb[e])) +
                   __bfloat162float(__ushort_as_bfloat16((unsigned short)pc[e]));
        }
        x[i] = v;
        s += v[0] + v[1] + v[2] + v[3];
    }
#pragma unroll
    for (int off = 1; off < 64; off <<= 1) s += __shfl_xor(s, off);
    float mu = s * (1.0f / HH);
    float vs = 0.f;
#pragma unroll
    for (int i = 0; i < 3; ++i)
#pragma unroll
        for (int e = 0; e < 4; ++e) { float d = x[i][e] - mu; vs += d * d; }
#pragma unroll
    for (int off = 1; off < 64; off <<= 1) vs += __shfl_xor(vs, off);
    float rstd = rsqrtf(vs * (1.0f / HH) + 1e-12f);
#pragma unroll
    for (int i = 0; i < 3; ++i) {
        int j = (lane + i * 64) * 4;
        f32x4 gg = *(const f32x4*)(g + j);
        f32x4 bb = *(const f32x4*)(bt + j);
        short4v yb;
#pragma unroll
        for (int e = 0; e < 4; ++e) {
            float y = (x[i][e] - mu) * rstd * gg[e] + bb[e];
            yb[e] = (short)__bfloat16_as_ushort(__float2bfloat16(y));
        }
        *(short4v*)(hb + base + j) = yb;
    }
}

// ---------------------------------------------------------------------------
// transpose-convert: in f32 [K][N] (row-major) -> out bf16 [N][K]
// 16B short8 stores (R17).
// ---------------------------------------------------------------------------
__global__ void __launch_bounds__(256) transp_conv(
    const float* __restrict__ in, bf16* __restrict__ out,
    int K, int N, size_t inStride, size_t outStride) {
    const float* src = in + (size_t)blockIdx.z * inStride;
    bf16* dst = out + (size_t)blockIdx.z * outStride;
    __shared__ float t[64][65];          // [n_local][k_local]
    int n0 = blockIdx.x * 64, k0 = blockIdx.y * 64;
    int tid = threadIdx.x;
    {
        int r = tid >> 4, c4 = (tid & 15) * 4;
#pragma unroll
        for (int i = 0; i < 4; ++i) {
            int kk = k0 + r + i * 16;    // always < K
            int n = n0 + c4;
            float4 v;
            if (n + 3 < N) {
                v = *(const float4*)(src + (size_t)kk * N + n);
            } else {
                v.x = (n + 0 < N) ? src[(size_t)kk * N + n + 0] : 0.f;
                v.y = (n + 1 < N) ? src[(size_t)kk * N + n + 1] : 0.f;
                v.z = (n + 2 < N) ? src[(size_t)kk * N + n + 2] : 0.f;
                v.w = (n + 3 < N) ? src[(size_t)kk * N + n + 3] : 0.f;
            }
            t[c4 + 0][r + i * 16] = v.x;
            t[c4 + 1][r + i * 16] = v.y;
            t[c4 + 2][r + i * 16] = v.z;
            t[c4 + 3][r + i * 16] = v.w;
        }
    }
    __syncthreads();
    {
        int r = tid >> 3, c8 = (tid & 7) * 8;    // 32 n-rows per pass, 16B/lane
#pragma unroll
        for (int i = 0; i < 2; ++i) {
            int nn = n0 + r + i * 32;
            if (nn < N) {
                short8 o;
#pragma unroll
                for (int e = 0; e < 8; ++e)
                    o[e] = (short)__bfloat16_as_ushort(
                        __float2bfloat16(t[r + i * 32][c8 + e]));
                *(short8*)(dst + (size_t)nn * K + k0 + c8) = o;
            }
        }
    }
}

// ---------------------------------------------------------------------------
// v slice of qkv [BS][ldv] bf16 -> vT [B][NH][DH][S] bf16 (short4 both ways)
// ---------------------------------------------------------------------------
__global__ void __launch_bounds__(256) vtrans_kernel(const bf16* __restrict__ v,
                                                     bf16* __restrict__ vT,
                                                     int ldv) {
    __shared__ bf16 t[64][68];           // [d_local][s_local]
    int s0 = blockIdx.x * 64, h = blockIdx.y, b = blockIdx.z;
    int tid = threadIdx.x;
    int r = tid >> 4, c4 = (tid & 15) * 4;
#pragma unroll
    for (int i = 0; i < 4; ++i) {
        int sr = r + i * 16;             // s_local
        short4v x = *(const short4v*)(v + ((size_t)(b * SS + s0 + sr)) * ldv +
                                      h * 64 + c4);
        t[c4 + 0][sr] = __ushort_as_bfloat16((unsigned short)x[0]);
        t[c4 + 1][sr] = __ushort_as_bfloat16((unsigned short)x[1]);
        t[c4 + 2][sr] = __ushort_as_bfloat16((unsigned short)x[2]);
        t[c4 + 3][sr] = __ushort_as_bfloat16((unsigned short)x[3]);
    }
    __syncthreads();
#pragma unroll
    for (int i = 0; i < 4; ++i) {
        int dr = r + i * 16;             // d_local
        short4v o;
        o[0] = (short)__bfloat16_as_ushort(t[dr][c4 + 0]);
        o[1] = (short)__bfloat16_as_ushort(t[dr][c4 + 1]);
        o[2] = (short)__bfloat16_as_ushort(t[dr][c4 + 2]);
        o[3] = (short)__bfloat16_as_ushort(t[dr][c4 + 3]);
        *(short4v*)(vT + (((size_t)(b * NHH + h)) * 64 + dr) * SS + s0 + c4) = o;
    }
}

// ---------------------------------------------------------------------------
// cls 256x256 GEMM, BK=32, 4-buffer depth-3 counted-vmcnt pipeline (R12).
// GROUP_M=8 raster (R18's GRPM=16 regressed: concurrency, not program order,
// governs L2 reuse). ~500 TF family ceiling; limiter is intra-wave
// ds_read<->MFMA serialization (five schedule variants all ~21% MfmaUtil).
// ---------------------------------------------------------------------------
template <int KK, int LDA, int LDB, int LDC, int NN>
__global__ void __launch_bounds__(512, 1) gemm256k_kernel(
    const bf16* __restrict__ A, const bf16* __restrict__ BT,
    const float* __restrict__ bias, float* __restrict__ Cout) {
    constexpr int ABYTES = 256 * 64;     // 256 rows x 32 bf16
    constexpr int BUF = 2 * ABYTES;      // A + B per buffer = 32KB
    constexpr int LPS = 4;               // 2 A + 2 B issues per thread
    __shared__ __align__(16) char smem[4 * BUF];
    int tid = threadIdx.x, lane = tid & 63, wid = tid >> 6;
    int mg = wid >> 2, ng = wid & 3;

    int gN = gridDim.x, gM = gridDim.y;
    int nwg = gN * gM;
    int bid = blockIdx.y * gN + blockIdx.x;
    int swz = ((nwg & 7) == 0) ? ((bid & 7) * (nwg >> 3) + (bid >> 3)) : bid;
    int width = 8 * gN;
    int grp = swz / width, rem = swz % width;
    int gh = min(8, gM - grp * 8);
    int by = grp * 8 + rem % gh;
    int bx = rem / gh;
    int m0 = by * 256, n0 = bx * 256;

    const char* Ab = (const char*)A;
    const char* Bb = (const char*)BT;

    f32x4 acc[8][4];
#pragma unroll
    for (int i = 0; i < 8; ++i)
#pragma unroll
        for (int j = 0; j < 4; ++j) acc[i][j] = Z4();

    auto stage = [&](int k0, int sel) {
#pragma unroll
        for (int i = 0; i < 2; ++i) {
            int lin = tid * 16 + i * 8192;
            int row = lin >> 6, slot = (lin >> 4) & 3;
            gload16(smem + sel * BUF + lin,
                    Ab + ((size_t)(m0 + row) * LDA + k0) * 2 +
                        ((slot ^ ((row >> 1) & 3)) << 4));
        }
#pragma unroll
        for (int i = 0; i < 2; ++i) {
            int lin = tid * 16 + i * 8192;
            int row = lin >> 6, slot = (lin >> 4) & 3;
            int nr = n0 + row;
            if constexpr (NN % 256 != 0) { if (nr >= NN) nr = NN - 1; }
            gload16(smem + sel * BUF + ABYTES + lin,
                    Bb + ((size_t)nr * LDB + k0) * 2 +
                        ((slot ^ ((row >> 1) & 3)) << 4));
        }
    };

    constexpr int T = KK / 32;
    stage(0, 0);
    stage(32, 1);
    stage(64, 2);
    waitvm<2 * LPS>();          // oldest (buf0) landed; buf1,2 in flight
    barrier_raw();

    for (int t = 0; t < T; ++t) {
        if (t + 3 < T) stage((t + 3) * 32, (t + 3) & 3);

        const char* Ar = smem + (t & 3) * BUF;
        const char* Br = Ar + ABYTES;
        short8 af[8], bfr[4];
#pragma unroll
        for (int i = 0; i < 8; ++i) {
            int ar = mg * 128 + i * 16 + (lane & 15);
            int slot = (lane >> 4) ^ ((ar >> 1) & 3);
            af[i] = *(const short8*)(Ar + ar * 64 + slot * 16);
        }
#pragma unroll
        for (int j = 0; j < 4; ++j) {
            int br = ng * 64 + j * 16 + (lane & 15);
            int slot = (lane >> 4) ^ ((br >> 1) & 3);
            bfr[j] = *(const short8*)(Br + br * 64 + slot * 16);
        }
        __builtin_amdgcn_s_setprio(1);
#pragma unroll
        for (int i = 0; i < 8; ++i)
#pragma unroll
            for (int j = 0; j < 4; ++j)
                acc[i][j] = __builtin_amdgcn_mfma_f32_16x16x32_bf16(
                    af[i], bfr[j], acc[i][j], 0, 0, 0);
        __builtin_amdgcn_s_setprio(0);

        if (t + 1 < T) {
            if (t + 4 < T)      waitvm<2 * LPS>();   // {t+2,t+3} stay in flight
            else if (t + 3 < T) waitvm<LPS>();
            else                waitvm<0>();
            barrier_raw();
        }
    }

    // direct-store epilogue (f32 out, N-tail guarded)
#pragma unroll
    for (int i = 0; i < 8; ++i)
#pragma unroll
        for (int r = 0; r < 4; ++r) {
            int m = m0 + mg * 128 + i * 16 + (lane >> 4) * 4 + r;
#pragma unroll
            for (int j = 0; j < 4; ++j) {
                int n = n0 + ng * 64 + j * 16 + (lane & 15);
                if ((NN % 256 == 0) || n < NN) {
                    float v = acc[i][j][r] + bias[n];
                    Cout[(size_t)m * LDC + n] = v;
                }
            }
        }
}

// ---------------------------------------------------------------------------
// bf16 MFMA GEMM (R10-proven): THREADS-parameterized 128-tile, 3-stage counted
// vmcnt pipeline, slot swizzle (row>>1)&3, XCD+GROUP_M=8 raster, direct stores.
// split-K over blockIdx.z; bf16 output honors zStride (R15).
// ---------------------------------------------------------------------------
#define GBK 32

template <int THREADS, int TBM, int TBN, int OUT_BF16, int ACT, int KK,
          int LDA, int LDB, int LDC, int NN, int NSTAGES>
__global__ void __launch_bounds__(THREADS) gemm_bf16_kernel(
    const bf16* __restrict__ A, const bf16* __restrict__ BT,
    const float* __restrict__ bias, void* __restrict__ Cout, size_t zStride) {
    constexpr int WN = (THREADS == 512) ? 4 : 2;
    constexpr int WM = 2;
    constexpr int MFRAG = TBM / WM / 16;
    constexpr int NFRAG = TBN / WN / 16;
    constexpr int ABYTES = TBM * GBK * 2;
    constexpr int BBYTES = TBN * GBK * 2;
    constexpr int A_ISS = ABYTES / (THREADS * 16);
    constexpr int B_ISS = BBYTES / (THREADS * 16);
    constexpr int LPS = A_ISS + B_ISS;
    __shared__ __align__(16) char smem[NSTAGES * (ABYTES + BBYTES)];
    char* Asm = smem;
    char* Bsm = smem + NSTAGES * ABYTES;
    int tid = threadIdx.x;
    int lane = tid & 63, wid = tid >> 6;

    int zz = blockIdx.z;
    const char* Ab = (const char*)(A + (size_t)zz * KK);
    const char* Bb = (const char*)(BT + (size_t)zz * KK);

    int gN = gridDim.x, gM = gridDim.y;
    int nwg = gN * gM;
    int bid = blockIdx.y * gN + blockIdx.x;
    int swz = ((nwg & 7) == 0) ? ((bid & 7) * (nwg >> 3) + (bid >> 3)) : bid;
    int width = 8 * gN;
    int grp = swz / width, rem = swz % width;
    int gh = min(8, gM - grp * 8);
    int by = grp * 8 + rem % gh;
    int bx = rem / gh;

    int m0 = by * TBM, n0 = bx * TBN;
    int wr = (wid / WN) * (TBM / WM);
    int wc = (wid % WN) * (TBN / WN);

    f32x4 acc[MFRAG][NFRAG];
#pragma unroll
    for (int i = 0; i < MFRAG; ++i)
#pragma unroll
        for (int j = 0; j < NFRAG; ++j) acc[i][j] = Z4();

    auto stage = [&](int k0, int sel) {
#pragma unroll
        for (int i = 0; i < A_ISS; ++i) {
            int lin = tid * 16 + i * (THREADS * 16);
            int row = lin >> 6, slot = (lin >> 4) & 3;
            gload16(Asm + sel * ABYTES + lin,
                    Ab + ((size_t)(m0 + row) * LDA + k0) * 2 +
                        ((slot ^ ((row >> 1) & 3)) << 4));
        }
#pragma unroll
        for (int i = 0; i < B_ISS; ++i) {
            int lin = tid * 16 + i * (THREADS * 16);
            int row = lin >> 6, slot = (lin >> 4) & 3;
            int nr = n0 + row;
            if constexpr (NN % TBN != 0) { if (nr >= NN) nr = NN - 1; }
            gload16(Bsm + sel * BBYTES + lin,
                    Bb + ((size_t)nr * LDB + k0) * 2 +
                        ((slot ^ ((row >> 1) & 3)) << 4));
        }
    };

    constexpr int T = KK / GBK;
#pragma unroll
    for (int s = 0; s < NSTAGES - 1; ++s) stage(s * GBK, s);
    waitvm<(NSTAGES - 2) * LPS>();
    barrier_raw();

    for (int t = 0; t < T; ++t) {
        if (t + NSTAGES - 1 < T)
            stage((t + NSTAGES - 1) * GBK, (t + NSTAGES - 1) % NSTAGES);

        const char* Ar = Asm + (t % NSTAGES) * ABYTES;
        const char* Br = Bsm + (t % NSTAGES) * BBYTES;
        short8 af[MFRAG], bfr[NFRAG];
#pragma unroll
        for (int i = 0; i < MFRAG; ++i) {
            int ar = wr + i * 16 + (lane & 15);
            int slot = (lane >> 4) ^ ((ar >> 1) & 3);
            af[i] = *(const short8*)(Ar + ar * 64 + slot * 16);
        }
#pragma unroll
        for (int j = 0; j < NFRAG; ++j) {
            int br = wc + j * 16 + (lane & 15);
            int slot = (lane >> 4) ^ ((br >> 1) & 3);
            bfr[j] = *(const short8*)(Br + br * 64 + slot * 16);
        }
#pragma unroll
        for (int i = 0; i < MFRAG; ++i)
#pragma unroll
            for (int j = 0; j < NFRAG; ++j)
                acc[i][j] = __builtin_amdgcn_mfma_f32_16x16x32_bf16(
                    af[i], bfr[j], acc[i][j], 0, 0, 0);

        if (t + 1 < T) {
            if (t + 2 < T) waitvm<LPS>();
            else           waitvm<0>();
            barrier_raw();
        }
    }

    bool nfull = (NN % TBN == 0) || (n0 + TBN <= NN);
#pragma unroll
    for (int i = 0; i < MFRAG; ++i) {
#pragma unroll
        for (int r = 0; r < 4; ++r) {
            int m = m0 + wr + i * 16 + (lane >> 4) * 4 + r;
#pragma unroll
            for (int j = 0; j < NFRAG; ++j) {
                int n = n0 + wc + j * 16 + (lane & 15);
                if (nfull || n < NN) {
                    float v = acc[i][j][r] + ((zz == 0) ? bias[n] : 0.f);
                    if (ACT) v = 0.5f * v * (1.0f + erff(v * 0.70710678118654752f));
                    if (OUT_BF16)
                        ((bf16*)Cout)[zz * zStride + (size_t)m * LDC + n] =
                            __float2bfloat16(v);
                    else
                        ((float*)Cout)[zz * zStride + (size_t)m * LDC + n] = v;
                }
            }
        }
    }
}

// ---------------------------------------------------------------------------
// flash attention, bf16 MFMA. Block = 64 q-rows (4 waves x 16), KV tiles of 64,
// double-buffered. Causal tile skip for q-blocks 1..5 (R13, bit-exact).
// ---------------------------------------------------------------------------
__global__ void __launch_bounds__(256) attn_mfma_kernel(
    const bf16* __restrict__ Q, const bf16* __restrict__ K,
    const bf16* __restrict__ VT, const int* __restrict__ ids,
    const int* __restrict__ qlen, bf16* __restrict__ att, int ld) {
    __shared__ __align__(16) bf16 Qs[64 * 64];
    __shared__ __align__(16) bf16 Ks[2][64 * 64];
    __shared__ __align__(16) bf16 Vs[2][64 * 64];
    __shared__ __align__(16) bf16 Ps[4 * 16 * 64];
    __shared__ float padj[2][64];

    int tid = threadIdx.x, lane = tid & 63, w = tid >> 6;
    int q0 = blockIdx.x * 64, h = blockIdx.y, b = blockIdx.z;
    int ql = qlen[b];

    int qb = q0 >> 6;
    int kvEnd = (qb >= 1 && qb <= 5) ? (qb + 1) * 64 : SS;

    const char* kbase0 = (const char*)K + ((size_t)(b * SS) * ld) * 2;
    const char* vbase0 = (const char*)VT + (((size_t)(b * NHH + h)) * 64) * SS * 2;

    auto stageKV = [&](int kv0, int sel) {
        int lin = tid * 16;
#pragma unroll
        for (int i = 0; i < 2; ++i, lin += 4096) {
            int row = lin >> 7, bir = lin & 127;
            int sbir = bir ^ ((row & 7) << 4);
            gload16((char*)Ks[sel] + lin,
                    kbase0 + (size_t)(kv0 + row) * (ld * 2) + h * 128 + sbir);
            gload16((char*)Vs[sel] + lin,
                    vbase0 + (size_t)row * (SS * 2) + (size_t)kv0 * 2 + sbir);
        }
        if (tid < 64)
            padj[sel][tid] = (ids[b * SS + kv0 + tid] != PAD_ID) ? 1.f : 0.f;
    };

    {
        const char* qbase =
            (const char*)Q + ((size_t)(b * SS + q0) * ld) * 2 + h * 128;
        int lin = tid * 16;
#pragma unroll
        for (int i = 0; i < 2; ++i, lin += 4096) {
            int row = lin >> 7, bir = lin & 127;
            int sbir = bir ^ ((row & 7) << 4);
            gload16((char*)Qs + lin, qbase + (size_t)row * (ld * 2) + sbir);
        }
    }
    stageKV(0, 0);
    int qrow_base = q0 + w * 16 + (lane >> 4) * 4;   // + r
    bool padq[4];
#pragma unroll
    for (int r = 0; r < 4; ++r)
        padq[r] = (ids[b * SS + qrow_base + r] != PAD_ID);

    wait_vm0_lgkm0_barrier();

    short8 aq[2];
#pragma unroll
    for (int ks = 0; ks < 2; ++ks) {
        int row = w * 16 + (lane & 15);
        int bir = ks * 64 + (lane >> 4) * 16;
        aq[ks] = *(const short8*)((const char*)Qs + row * 128 +
                                  (bir ^ ((row & 7) << 4)));
    }

    float m_run[4], l_run[4];
    f32x4 accO[4];
#pragma unroll
    for (int r = 0; r < 4; ++r) { m_run[r] = -1e30f; l_run[r] = 0.f; }
#pragma unroll
    for (int d = 0; d < 4; ++d) accO[d] = Z4();

    int cur = 0;
    for (int kv0 = 0; kv0 < kvEnd; kv0 += 64) {
        if (kv0 + 64 < kvEnd) stageKV(kv0 + 64, cur ^ 1);
        const char* kb = (const char*)Ks[cur];
        const char* vb = (const char*)Vs[cur];

        f32x4 accS[4];
        __builtin_amdgcn_s_setprio(1);
#pragma unroll
        for (int nf = 0; nf < 4; ++nf) {
            f32x4 z = Z4();
#pragma unroll
            for (int ks = 0; ks < 2; ++ks) {
                int row = nf * 16 + (lane & 15);
                int bir = ks * 64 + (lane >> 4) * 16;
                short8 bk = *(const short8*)(kb + row * 128 +
                                             (bir ^ ((row & 7) << 4)));
                z = __builtin_amdgcn_mfma_f32_16x16x32_bf16(aq[ks], bk, z, 0, 0, 0);
            }
            accS[nf] = z;
        }
        __builtin_amdgcn_s_setprio(0);

        float p[4][4];        // [r][nf]
#pragma unroll
        for (int r = 0; r < 4; ++r) {
            int qg = qrow_base + r;
            float mx = -1e30f;
#pragma unroll
            for (int nf = 0; nf < 4; ++nf) {
                int j = kv0 + nf * 16 + (lane & 15);
                bool ok = padq[r] && (padj[cur][nf * 16 + (lane & 15)] != 0.f) &&
                          ((qg < ql) || (j < ql) || (j <= qg));
                float s = accS[nf][r] * 0.125f + (ok ? 0.f : -1e9f);
                p[r][nf] = s;
                mx = fmaxf(mx, s);
            }
#pragma unroll
            for (int off = 1; off < 16; off <<= 1)
                mx = fmaxf(mx, __shfl_xor(mx, off));
            float mnew = fmaxf(m_run[r], mx);
            float fac = __expf(m_run[r] - mnew);
            m_run[r] = mnew;
            float rs = 0.f;
#pragma unroll
            for (int nf = 0; nf < 4; ++nf) {
                float e = __expf(p[r][nf] - mnew);
                p[r][nf] = e;
                rs += e;
            }
#pragma unroll
            for (int off = 1; off < 16; off <<= 1)
                rs += __shfl_xor(rs, off);
            l_run[r] = l_run[r] * fac + rs;
#pragma unroll
            for (int df = 0; df < 4; ++df) accO[df][r] *= fac;
        }

#pragma unroll
        for (int r = 0; r < 4; ++r) {
            int prow = (lane >> 4) * 4 + r;
#pragma unroll
            for (int nf = 0; nf < 4; ++nf) {
                int c = nf * 16 + (lane & 15);
                int byte = (c * 2) ^ ((prow & 7) << 4);
                *(bf16*)((char*)Ps + w * 2048 + prow * 128 + byte) =
                    __float2bfloat16(p[r][nf]);
            }
        }
        asm volatile("s_waitcnt lgkmcnt(0)" ::: "memory");
        __builtin_amdgcn_sched_barrier(0);

        __builtin_amdgcn_s_setprio(1);
#pragma unroll
        for (int ks = 0; ks < 2; ++ks) {
            int prow = lane & 15;
            int bir = ks * 64 + (lane >> 4) * 16;
            short8 ap = *(const short8*)((const char*)Ps + w * 2048 + prow * 128 +
                                         (bir ^ ((prow & 7) << 4)));
#pragma unroll
            for (int df = 0; df < 4; ++df) {
                int vrow = df * 16 + (lane & 15);
                short8 bv = *(const short8*)(vb + vrow * 128 +
                                             (bir ^ ((vrow & 7) << 4)));
                accO[df] = __builtin_amdgcn_mfma_f32_16x16x32_bf16(
                    ap, bv, accO[df], 0, 0, 0);
            }
        }
        __builtin_amdgcn_s_setprio(0);

        if (kv0 + 64 < kvEnd) wait_vm0_lgkm0_barrier();
        cur ^= 1;
    }

#pragma unroll
    for (int r = 0; r < 4; ++r) {
        int qg = qrow_base + r;
        float inv = 1.0f / l_run[r];
#pragma unroll
        for (int df = 0; df < 4; ++df) {
            int d = df * 16 + (lane & 15);
            att[((size_t)(b * SS) + qg) * HH + h * 64 + d] =
                __float2bfloat16(accO[df][r] * inv);
        }
    }
}

// ---------------------------------------------------------------------------
// launch
// ---------------------------------------------------------------------------
extern "C" void kernel_launch(void* const* d_in, const int* in_sizes, int n_in,
                              void* d_out, int out_size, void* d_ws, size_t ws_size,
                              hipStream_t stream) {
    const int*   ids      = (const int*)d_in[0];
    const float* word_emb = (const float*)d_in[1];
    const float* pos_emb  = (const float*)d_in[2];
    const float* type_emb = (const float*)d_in[3];
    const float* emb_ln_g = (const float*)d_in[4];
    const float* emb_ln_b = (const float*)d_in[5];
    const float* attn_w   = (const float*)d_in[6];
    const float* attn_b   = (const float*)d_in[7];
    const float* ln1_g    = (const float*)d_in[8];
    const float* ln1_b    = (const float*)d_in[9];
    const float* ffn_w1   = (const float*)d_in[10];
    const float* ffn_b1   = (const float*)d_in[11];
    const float* ffn_w2   = (const float*)d_in[12];
    const float* ffn_b2   = (const float*)d_in[13];
    const float* ln2_g    = (const float*)d_in[14];
    const float* ln2_b    = (const float*)d_in[15];
    const float* cls_w    = (const float*)d_in[16];
    const float* cls_b    = (const float*)d_in[17];
    float* out = (float*)d_out;

    // ---- workspace layout ----
    char* base = (char*)d_ws;
    size_t off = 0;
    auto take = [&](size_t bytes) {
        char* r = base + off;
        off += (bytes + 255) & ~(size_t)255;
        return r;
    };
    bf16*  projb = (bf16*)take(2 * BSH * 2);      // bf16 split-K halves
    float* spare = (float*)take(BSH * 4);          // reusable span head (cls wrot)
    bf16*  qkv   = (bf16*)take((size_t)BS * QKVN * 2);  // [BS][2304]
    bf16*  vT    = (bf16*)take(BSH * 2);
    bf16*  attb  = (bf16*)take(BSH * 2);
    bf16*  ffb   = (bf16*)take(BSFF * 2);          // end of reusable span
    bf16*  hb    = (bf16*)take(BSH * 2);
    int*   qlen  = (int*)take(256);
    size_t commonEnd = off;

    const size_t szAttnW = (size_t)48 * HH * HH * 2;
    const size_t szW1    = (size_t)LL * HH * FFF * 2;
    const size_t szCls   = (size_t)VV * HH * 2;
    const size_t fullNeed = commonEnd + szAttnW + 2 * szW1 + szCls;
    bool fullMode = (ws_size >= fullNeed);

    bf16 *wAttnT = nullptr, *w1T = nullptr, *w2T = nullptr, *clsT = nullptr, *wrot = nullptr;
    if (fullMode) {
        wAttnT = (bf16*)take(szAttnW);
        w1T    = (bf16*)take(szW1);
        w2T    = (bf16*)take(szW1);
        clsT   = (bf16*)take(szCls);
    } else {
        wrot = (bf16*)take((size_t)HH * FFF * 2);   // rotating buffer
        clsT = (bf16*)spare;                         // cls weight -> dead span
    }

    auto convw = [&](const float* src, bf16* dst, int K, int N) {
        dim3 g((N + 63) / 64, K / 64, 1);
        transp_conv<<<g, 256, 0, stream>>>(src, dst, K, N, (size_t)0, (size_t)0);
    };

    qlen_kernel<<<BB, 256, 0, stream>>>(ids, qlen);

    if (fullMode) {
        transp_conv<<<dim3(12, 12, 48), 256, 0, stream>>>(
            attn_w, wAttnT, HH, HH, (size_t)HH * HH, (size_t)HH * HH);
        transp_conv<<<dim3(FFF / 64, HH / 64, LL), 256, 0, stream>>>(
            ffn_w1, w1T, HH, FFF, (size_t)HH * FFF, (size_t)HH * FFF);
        transp_conv<<<dim3(HH / 64, FFF / 64, LL), 256, 0, stream>>>(
            ffn_w2, w2T, FFF, HH, (size_t)HH * FFF, (size_t)HH * FFF);
        transp_conv<<<dim3((VV + 63) / 64, HH / 64, 1), 256, 0, stream>>>(
            cls_w, clsT, HH, VV, (size_t)0, (size_t)0);
    }

    embed_ln_kernel<<<BS / 4, 256, 0, stream>>>(ids, word_emb, pos_emb, type_emb,
                                                emb_ln_g, emb_ln_b, hb);

    dim3 gQKV(QKVN / 128, BS / 128, 1);          // 576, 512-thr
    dim3 gWo(HH / 64, BS / 128, 2);              // 768 (split-K x2), 256-thr
    dim3 gFF1(FFF / 128, BS / 128, 1);           // 768, 512-thr
    dim3 gFF2(HH / 64, BS / 128, 2);             // 768 (split-K x2), 256-thr
    dim3 gCls((VV + 255) / 256, BS / 256, 1);    // 83 x 16 = 1328, 512-thr
    dim3 gAttn(SS / 64, NHH, BB);                // 768
    dim3 gVT(SS / 64, NHH, BB);
    dim3 gLN(BS / 4, 1, 1);                      // 1024, wave-per-token

    for (int l = 0; l < LL; ++l) {
        const float* wq32 = attn_w + (size_t)l * 4 * HH * HH;
        const float* wo32 = wq32 + (size_t)3 * HH * HH;
        const float* bqkv = attn_b + (size_t)l * 4 * HH;   // q,k,v contiguous
        const float* bo   = bqkv + 3 * HH;

        bf16 *wqkvT, *woT, *w1Tl, *w2Tl;
        if (fullMode) {
            wqkvT = wAttnT + (size_t)(l * 4) * HH * HH;    // [2304][768]
            woT   = wAttnT + (size_t)(l * 4 + 3) * HH * HH;
            w1Tl  = w1T + (size_t)l * HH * FFF;
            w2Tl  = w2T + (size_t)l * HH * FFF;
        } else {
            wqkvT = woT = w1Tl = w2Tl = wrot;
        }

        if (!fullMode) {
            convw(wq32, wrot, HH, HH);
            convw(wq32 + (size_t)HH * HH, wrot + (size_t)HH * HH, HH, HH);
            convw(wq32 + (size_t)2 * HH * HH, wrot + (size_t)2 * HH * HH, HH, HH);
        }
        gemm_bf16_kernel<512, 128, 128, 1, 0, HH, HH, HH, QKVN, QKVN, 3>
            <<<gQKV, 512, 0, stream>>>(hb, wqkvT, bqkv, qkv, 0);

        vtrans_kernel<<<gVT, 256, 0, stream>>>(qkv + 2 * HH, vT, QKVN);
        attn_mfma_kernel<<<gAttn, 256, 0, stream>>>(
            qkv, qkv + HH, vT, ids, qlen, attb, QKVN);

        if (!fullMode) convw(wo32, wrot, HH, HH);
        gemm_bf16_kernel<256, 128, 64, 1, 0, HH / 2, HH, HH, HH, HH, 3>
            <<<gWo, 256, 0, stream>>>(attb, woT, bo, projb, BSH);
        add_ln_kernel<<<gLN, 256, 0, stream>>>(hb, projb, projb + BSH,
                                               ln1_g + (size_t)l * HH,
                                               ln1_b + (size_t)l * HH);

        if (!fullMode) convw(ffn_w1 + (size_t)l * HH * FFF, wrot, HH, FFF);
        gemm_bf16_kernel<512, 128, 128, 1, 1, HH, HH, HH, FFF, FFF, 3>
            <<<gFF1, 512, 0, stream>>>(hb, w1Tl, ffn_b1 + (size_t)l * FFF, ffb, 0);
        if (!fullMode) convw(ffn_w2 + (size_t)l * HH * FFF, wrot, FFF, HH);
        gemm_bf16_kernel<256, 128, 64, 1, 0, FFF / 2, FFF, FFF, HH, HH, 3>
            <<<gFF2, 256, 0, stream>>>(ffb, w2Tl, ffn_b2 + (size_t)l * HH, projb,
                                       BSH);
        add_ln_kernel<<<gLN, 256, 0, stream>>>(hb, projb, projb + BSH,
                                               ln2_g + (size_t)l * HH,
                                               ln2_b + (size_t)l * HH);
    }

    if (!fullMode) convw(cls_w, clsT, HH, VV);
    gemm256k_kernel<HH, HH, HH, VV, VV>
        <<<gCls, 512, 0, stream>>>(hb, clsT, cls_b, out);
}